// Round 2
// baseline (1102.318 us; speedup 1.0000x reference)
//
#include <hip/hip_runtime.h>
#include <hip/hip_bf16.h>

#define HIDN   64
#define NHEADS 8
#define DHEAD  8
#define NLAY   2
#define BB     4
#define SS     12
#define NNODE  512
#define NEDGE  8192
#define XELEMS (BB * SS * NNODE * 3)      // 73728
#define SCALE  0.35355339059327373f       // 1/sqrt(8)

typedef unsigned short u16;
typedef unsigned int   u32;

__device__ __forceinline__ float b2f(u16 u) {
    union { u32 i; float f; } c; c.i = ((u32)u) << 16; return c.f;
}

// -------- dtype detection: bf16 buffer decoded as bf16 has max|v|~4.5;
// -------- fp32 buffer halves decoded as bf16 hit |v|>1e30 / NaN w.p. ~1.
__global__ void detect_kernel(const u16* __restrict__ x, int* __restrict__ flag) {
    int t = threadIdx.x;
    int bad = 0;
    for (int i = t; i < XELEMS; i += 256) {
        float v = fabsf(b2f(x[i]));
        if (!(v <= 100.f)) bad = 1;   // catches huge AND NaN
    }
    if (bad) atomicOr(flag, 1);       // flag=1 -> inputs are fp32
}

// ---------------- input staging: decode 17 tensors to fp32 per flag ----------
struct CvtArgs {
    const void* src[17];
    float*      dst[17];
    int         n[17];
};

__global__ void convert_kernel(CvtArgs a, const int* __restrict__ flagp) {
    int fl = *flagp;
    int y  = blockIdx.y;
    int t  = blockIdx.x * blockDim.x + threadIdx.x;
    if (t < a.n[y]) {
        float v = fl ? ((const float*)a.src[y])[t] : b2f(((const u16*)a.src[y])[t]);
        a.dst[y][t] = v;
    }
}

// ---------------- edge mask as bitmask: word[m][n>>5] bit (n&31) -------------
__global__ void scatter_mask_kernel(const int* __restrict__ ei, u32* __restrict__ maskbits) {
    int e = blockIdx.x * blockDim.x + threadIdx.x;
    if (e < NEDGE) {
        int n = ei[e];          // edge_index[0][e] -> attention row (query)
        int m = ei[NEDGE + e];  // edge_index[1][e] -> attention col (key)
        atomicOr(&maskbits[m * 16 + (n >> 5)], 1u << (n & 31));
    }
}

// ---------------- input projection: [B,S,N,3] @ WinT + b -> h [B,S,N,64] -----
__global__ void input_proj_kernel(const float* __restrict__ x, const float* __restrict__ W,
                                  const float* __restrict__ b, float* __restrict__ h) {
    int t = blockIdx.x * blockDim.x + threadIdx.x;  // row*64 + j
    int row = t >> 6, j = t & 63;
    float x0 = x[row * 3];
    float x1 = x[row * 3 + 1];
    float x2 = x[row * 3 + 2];
    h[t] = b[j] + x0 * W[j * 3] + x1 * W[j * 3 + 1] + x2 * W[j * 3 + 2];
}

// ---------------- q/k/v projection: one 64-thread block per row --------------
__global__ __launch_bounds__(64) void qkv_kernel(
    const float* __restrict__ h,
    const float* __restrict__ Wq, const float* __restrict__ bq,
    const float* __restrict__ Wk, const float* __restrict__ bk,
    const float* __restrict__ Wv, const float* __restrict__ bv,
    float* __restrict__ q, float* __restrict__ k, float* __restrict__ v) {
    __shared__ float hs[HIDN];
    int row = blockIdx.x;
    int j   = threadIdx.x;
    hs[j] = h[row * HIDN + j];
    __syncthreads();
    float aq = bq[j], ak = bk[j], av = bv[j];
    const float* wq = Wq + j * HIDN;
    const float* wk = Wk + j * HIDN;
    const float* wv = Wv + j * HIDN;
#pragma unroll
    for (int i = 0; i < HIDN; i += 4) {
        float4 q4 = *(const float4*)(wq + i);
        float4 k4 = *(const float4*)(wk + i);
        float4 v4 = *(const float4*)(wv + i);
        float h0 = hs[i], h1 = hs[i + 1], h2 = hs[i + 2], h3 = hs[i + 3];
        aq += h0 * q4.x + h1 * q4.y + h2 * q4.z + h3 * q4.w;
        ak += h0 * k4.x + h1 * k4.y + h2 * k4.z + h3 * k4.w;
        av += h0 * v4.x + h1 * v4.y + h2 * v4.z + h3 * v4.w;
    }
    q[row * HIDN + j] = aq;
    k[row * HIDN + j] = ak;
    v[row * HIDN + j] = av;
}

// ---------------- spatial attention: thread per (b,s,h,n), loop m ------------
// lane = n  =>  k/v addresses wave-uniform (broadcast), maskbits 2 words/wave
__global__ __launch_bounds__(256) void spatial_attn_kernel(
    const float* __restrict__ q, const float* __restrict__ k, const float* __restrict__ v,
    const u32* __restrict__ maskbits, float* __restrict__ h) {
    int t  = blockIdx.x * blockDim.x + threadIdx.x;  // ((bs*H + hd)*N + n)
    int n  = t & (NNODE - 1);
    int hd = (t >> 9) & 7;
    int bs = t >> 12;  // b*S + s, 0..47
    int rowbase = __builtin_amdgcn_readfirstlane(bs * (NNODE * HIDN) + hd * DHEAD);
    const float* kb = k + rowbase;
    const float* vb = v + rowbase;
    const float* qp = q + rowbase + n * HIDN;
    float4 qa = *(const float4*)qp;
    float4 qc = *(const float4*)(qp + 4);
    int word = n >> 5;
    u32 bitp = (u32)(n & 31);
    float a0 = 0.f, a1 = 0.f, a2 = 0.f, a3 = 0.f, a4 = 0.f, a5 = 0.f, a6 = 0.f, a7 = 0.f;
    float l = 0.f;
#pragma unroll 4
    for (int m = 0; m < NNODE; ++m) {
        const float* kp = kb + m * HIDN;
        float4 ka = *(const float4*)kp;
        float4 kc = *(const float4*)(kp + 4);
        float s = qa.x * ka.x + qa.y * ka.y + qa.z * ka.z + qa.w * ka.w +
                  qc.x * kc.x + qc.y * kc.y + qc.z * kc.z + qc.w * kc.w;
        u32 w = maskbits[m * 16 + word];
        // scores are O(0.1): exp cannot overflow; masked -> exactly 0 weight
        float e = ((w >> bitp) & 1u) ? __expf(s * SCALE) : 0.f;
        l += e;
        const float* vp = vb + m * HIDN;
        float4 va = *(const float4*)vp;
        float4 vc = *(const float4*)(vp + 4);
        a0 += e * va.x; a1 += e * va.y; a2 += e * va.z; a3 += e * va.w;
        a4 += e * vc.x; a5 += e * vc.y; a6 += e * vc.z; a7 += e * vc.w;
    }
    if (l == 0.f) {
        // fully-masked row: reference softmax over identical -1e9 -> uniform mean(v)
        for (int m = 0; m < NNODE; ++m) {
            const float* vp = vb + m * HIDN;
            float4 va = *(const float4*)vp;
            float4 vc = *(const float4*)(vp + 4);
            a0 += va.x; a1 += va.y; a2 += va.z; a3 += va.w;
            a4 += vc.x; a5 += vc.y; a6 += vc.z; a7 += vc.w;
        }
        l = (float)NNODE;
    }
    float inv = 1.f / l;
    float* op = h + rowbase + n * HIDN;
    *(float4*)op       = make_float4(a0 * inv, a1 * inv, a2 * inv, a3 * inv);
    *(float4*)(op + 4) = make_float4(a4 * inv, a5 * inv, a6 * inv, a7 * inv);
}

// ---------------- temporal attention: thread per (b,s,n,h), loop t (S=12) ----
__global__ __launch_bounds__(256) void temporal_attn_kernel(
    const float* __restrict__ q, const float* __restrict__ k, const float* __restrict__ v,
    float* __restrict__ h) {
    int t    = blockIdx.x * blockDim.x + threadIdx.x;  // ((b*S+sq)*N + n)*8 + hd
    int hd   = t & 7;
    int n    = (t >> 3) & (NNODE - 1);
    int rest = t >> 12;  // b*S + sq
    int b    = rest / SS;
    const float* qp = q + (rest * NNODE + n) * HIDN + hd * DHEAD;
    float4 qa = *(const float4*)qp;
    float4 qc = *(const float4*)(qp + 4);
    const float* kbase = k + (b * SS * NNODE + n) * HIDN + hd * DHEAD;
    const float* vbase = v + (b * SS * NNODE + n) * HIDN + hd * DHEAD;
    float s[SS];
#pragma unroll
    for (int tt = 0; tt < SS; ++tt) {
        const float* kp = kbase + tt * (NNODE * HIDN);
        float4 ka = *(const float4*)kp;
        float4 kc = *(const float4*)(kp + 4);
        s[tt] = (qa.x * ka.x + qa.y * ka.y + qa.z * ka.z + qa.w * ka.w +
                 qc.x * kc.x + qc.y * kc.y + qc.z * kc.z + qc.w * kc.w) * SCALE;
    }
    float mx = s[0];
#pragma unroll
    for (int tt = 1; tt < SS; ++tt) mx = fmaxf(mx, s[tt]);
    float l = 0.f;
#pragma unroll
    for (int tt = 0; tt < SS; ++tt) { s[tt] = __expf(s[tt] - mx); l += s[tt]; }
    float a0 = 0.f, a1 = 0.f, a2 = 0.f, a3 = 0.f, a4 = 0.f, a5 = 0.f, a6 = 0.f, a7 = 0.f;
#pragma unroll
    for (int tt = 0; tt < SS; ++tt) {
        const float* vp = vbase + tt * (NNODE * HIDN);
        float4 va = *(const float4*)vp;
        float4 vc = *(const float4*)(vp + 4);
        float e = s[tt];
        a0 += e * va.x; a1 += e * va.y; a2 += e * va.z; a3 += e * va.w;
        a4 += e * vc.x; a5 += e * vc.y; a6 += e * vc.z; a7 += e * vc.w;
    }
    float inv = 1.f / l;
    float* op = h + (rest * NNODE + n) * HIDN + hd * DHEAD;
    *(float4*)op       = make_float4(a0 * inv, a1 * inv, a2 * inv, a3 * inv);
    *(float4*)(op + 4) = make_float4(a4 * inv, a5 * inv, a6 * inv, a7 * inv);
}

// ---------------- output projection: h[:, S-1] @ WoutT + bout ----------------
__global__ void out_proj_kernel(const float* __restrict__ h, const float* __restrict__ W,
                                const float* __restrict__ b, void* __restrict__ out,
                                const int* __restrict__ flagp) {
    int t = blockIdx.x * blockDim.x + threadIdx.x;  // (b*N + n)*3 + c
    if (t >= BB * NNODE * 3) return;
    int c  = t % 3;
    int bn = t / 3;
    int n  = bn & (NNODE - 1);
    int bb = bn >> 9;
    const float* hp = h + ((bb * SS + (SS - 1)) * NNODE + n) * HIDN;
    const float* wp = W + c * HIDN;
    float a = b[c];
#pragma unroll
    for (int i = 0; i < HIDN; i += 4) {
        float4 h4 = *(const float4*)(hp + i);
        float4 w4 = *(const float4*)(wp + i);
        a += h4.x * w4.x + h4.y * w4.y + h4.z * w4.z + h4.w * w4.w;
    }
    if (*flagp) ((float*)out)[t] = a;
    else        ((__hip_bfloat16*)out)[t] = __float2bfloat16(a);
}

extern "C" void kernel_launch(void* const* d_in, const int* in_sizes, int n_in,
                              void* d_out, int out_size, void* d_ws, size_t ws_size,
                              hipStream_t stream) {
    const int* ei = (const int*)d_in[1];

    float* ws = (float*)d_ws;
    // layout (float offsets)
    int*   flag   = (int*)ws;              // 0   (64 floats reserved)
    float* Win_f  = ws + 64;               // 192
    float* bin_f  = ws + 256;              // 64
    float* Wqs_f  = ws + 320;              // 8192 (both layers)
    float* bqs_f  = ws + 8512;             // 128
    float* Wks_f  = ws + 8640;             // 8192
    float* bks_f  = ws + 16832;            // 128
    float* Wvs_f  = ws + 16960;            // 8192
    float* bvs_f  = ws + 25152;            // 128
    float* Wqt_f  = ws + 25280;            // 8192
    float* bqt_f  = ws + 33472;            // 128
    float* Wkt_f  = ws + 33600;            // 8192
    float* bkt_f  = ws + 41792;            // 128
    float* Wvt_f  = ws + 41920;            // 8192
    float* bvt_f  = ws + 50112;            // 128
    float* Wout_f = ws + 50240;            // 192
    float* bout_f = ws + 50432;            // 64 (uses 3)
    float* xf     = ws + 50496;            // 73728
    u32*   maskbits = (u32*)(ws + 124224); // 8192 u32
    const int ROWS = BB * SS * NNODE;      // 24576
    float* hbuf = ws + 132416;             // 1572864 each
    float* qbuf = hbuf + ROWS * HIDN;
    float* kbuf = qbuf + ROWS * HIDN;
    float* vbuf = kbuf + ROWS * HIDN;
    // total ws use: ~25.7 MB

    CvtArgs ca;
    const void* srcs[17] = {d_in[2], d_in[3], d_in[4], d_in[5], d_in[6], d_in[7],
                            d_in[8], d_in[9], d_in[10], d_in[11], d_in[12], d_in[13],
                            d_in[14], d_in[15], d_in[16], d_in[17], d_in[0]};
    float* dsts[17] = {Win_f, bin_f, Wqs_f, bqs_f, Wks_f, bks_f, Wvs_f, bvs_f,
                       Wqt_f, bqt_f, Wkt_f, bkt_f, Wvt_f, bvt_f, Wout_f, bout_f, xf};
    int    ns[17]   = {192, 64, 8192, 128, 8192, 128, 8192, 128,
                       8192, 128, 8192, 128, 8192, 128, 192, 3, XELEMS};
    for (int i = 0; i < 17; ++i) { ca.src[i] = srcs[i]; ca.dst[i] = dsts[i]; ca.n[i] = ns[i]; }

    hipMemsetAsync(flag, 0, sizeof(int), stream);
    hipMemsetAsync(maskbits, 0, 8192 * sizeof(u32), stream);
    detect_kernel<<<1, 256, 0, stream>>>((const u16*)d_in[0], flag);
    convert_kernel<<<dim3((XELEMS + 255) / 256, 17), 256, 0, stream>>>(ca, flag);
    scatter_mask_kernel<<<NEDGE / 256, 256, 0, stream>>>(ei, maskbits);
    input_proj_kernel<<<ROWS * HIDN / 256, 256, 0, stream>>>(xf, Win_f, bin_f, hbuf);

    const int ATTN_BLOCKS = BB * SS * NHEADS * NNODE / 256;  // 768
    for (int l = 0; l < NLAY; ++l) {
        // spatial
        qkv_kernel<<<ROWS, 64, 0, stream>>>(hbuf,
            Wqs_f + l * 4096, bqs_f + l * 64,
            Wks_f + l * 4096, bks_f + l * 64,
            Wvs_f + l * 4096, bvs_f + l * 64,
            qbuf, kbuf, vbuf);
        spatial_attn_kernel<<<ATTN_BLOCKS, 256, 0, stream>>>(qbuf, kbuf, vbuf, maskbits, hbuf);
        // temporal
        qkv_kernel<<<ROWS, 64, 0, stream>>>(hbuf,
            Wqt_f + l * 4096, bqt_f + l * 64,
            Wkt_f + l * 4096, bkt_f + l * 64,
            Wvt_f + l * 4096, bvt_f + l * 64,
            qbuf, kbuf, vbuf);
        temporal_attn_kernel<<<ATTN_BLOCKS, 256, 0, stream>>>(qbuf, kbuf, vbuf, hbuf);
    }
    out_proj_kernel<<<(BB * NNODE * 3 + 255) / 256, 256, 0, stream>>>(
        hbuf, Wout_f, bout_f, d_out, flag);
}

// Round 3
// 453.871 us; speedup vs baseline: 2.4287x; 2.4287x over previous
//
#include <hip/hip_runtime.h>
#include <hip/hip_bf16.h>

#define HIDN   64
#define NHEADS 8
#define DHEAD  8
#define NLAY   2
#define BB     4
#define SS     12
#define NNODE  512
#define NEDGE  8192
#define XELEMS (BB * SS * NNODE * 3)      // 73728
#define ROWS   (BB * SS * NNODE)          // 24576
#define SCALE  0.35355339059327373f       // 1/sqrt(8)

typedef unsigned short u16;
typedef unsigned int   u32;

__device__ __forceinline__ float b2f(u16 u) {
    union { u32 i; float f; } c; c.i = ((u32)u) << 16; return c.f;
}

// -------- dtype detection: bf16 buffer decoded as bf16 has max|v|~4.5;
// -------- fp32 buffer halves decoded as bf16 hit |v|>1e30 / NaN w.p. ~1.
__global__ void detect_kernel(const u16* __restrict__ x, int* __restrict__ flag) {
    int i0 = blockIdx.x * 256 + threadIdx.x;
    int bad = 0;
    for (int i = i0; i < XELEMS; i += 64 * 256) {
        float v = fabsf(b2f(x[i]));
        if (!(v <= 100.f)) bad = 1;   // catches huge AND NaN
    }
    if (bad) atomicOr(flag, 1);       // flag=1 -> inputs are fp32
}

// ---------------- input staging: decode 17 tensors to fp32 per flag ----------
struct CvtArgs {
    const void* src[17];
    float*      dst[17];
    int         n[17];
};

__global__ void convert_kernel(CvtArgs a, const int* __restrict__ flagp) {
    int fl = *flagp;
    int y  = blockIdx.y;
    int t  = blockIdx.x * blockDim.x + threadIdx.x;
    if (t < a.n[y]) {
        float v = fl ? ((const float*)a.src[y])[t] : b2f(((const u16*)a.src[y])[t]);
        a.dst[y][t] = v;
    }
}

// ---------------- pack W[l][j][i] (fp32 staged) -> wT[l][i][192], bias[l][192]
__global__ void pack_kernel(const float* __restrict__ Wq, const float* __restrict__ bq,
                            const float* __restrict__ Wk, const float* __restrict__ bk,
                            const float* __restrict__ Wv, const float* __restrict__ bv,
                            float* __restrict__ wT, float* __restrict__ bp) {
    int l = blockIdx.y;
    int t = blockIdx.x * 256 + threadIdx.x;   // 0..12287
    int i = t / 192, j = t - i * 192;
    int c = j >> 6, cc = j & 63;
    const float* W = (c == 0) ? Wq : (c == 1) ? Wk : Wv;
    wT[l * 12288 + t] = W[l * 4096 + cc * 64 + i];
    if (i == 0) {
        const float* B = (c == 0) ? bq : (c == 1) ? bk : bv;
        bp[l * 192 + j] = B[l * 64 + cc];
    }
}

// ---------------- edge mask, transposed bitmask: maskT[n][m>>5] bit (m&31) ---
__global__ void scatter_mask_kernel(const int* __restrict__ ei, u32* __restrict__ maskT) {
    int e = blockIdx.x * blockDim.x + threadIdx.x;
    if (e < NEDGE) {
        int n = ei[e];          // query row
        int m = ei[NEDGE + e];  // key col
        atomicOr(&maskT[n * 16 + (m >> 5)], 1u << (m & 31));
    }
}

// ---------------- input projection: [B,S,N,3] @ WinT + b -> h [ROWS,64] ------
__global__ void input_proj_kernel(const float* __restrict__ x, const float* __restrict__ W,
                                  const float* __restrict__ b, float* __restrict__ h) {
    int t = blockIdx.x * blockDim.x + threadIdx.x;  // row*64 + j
    int row = t >> 6, j = t & 63;
    float x0 = x[row * 3];
    float x1 = x[row * 3 + 1];
    float x2 = x[row * 3 + 2];
    h[t] = b[j] + x0 * W[j * 3] + x1 * W[j * 3 + 1] + x2 * W[j * 3 + 2];
}

// ---------------- fused q/k/v GEMM: [ROWS,64] x [64,192] + bias --------------
// block: 64 rows x 192 cols, 256 threads, 4x12 acc/thread. W staged in halves.
// spatial_layout=1 -> outputs [bs][hd][n][8]; else row-major [row][64].
__global__ __launch_bounds__(256) void qkv_gemm_kernel(
    const float* __restrict__ h, const float* __restrict__ wT,
    const float* __restrict__ bias,
    float* __restrict__ q, float* __restrict__ k, float* __restrict__ v,
    int spatial_layout) {
    __shared__ float hT[64][68];    // [i][r], padded (+4) -> 2-way max
    __shared__ float wS[32][192];   // [i-half][j]
    __shared__ float bS[192];
    int t = threadIdx.x;
    int row0 = blockIdx.x * 64;
    // stage A transposed: 64 rows x 64 i
    {
        int r = t & 63, ic = t >> 6;        // ic 0..3 -> i0 = ic*16
        const float* hp = h + (row0 + r) * 64 + ic * 16;
#pragma unroll
        for (int c = 0; c < 4; ++c) {
            float4 hv = *(const float4*)(hp + c * 4);
            int i = ic * 16 + c * 4;
            hT[i][r] = hv.x; hT[i + 1][r] = hv.y; hT[i + 2][r] = hv.z; hT[i + 3][r] = hv.w;
        }
    }
    // stage W phase 0 + bias
    {
        const float4* src = (const float4*)wT;
        float4* dst = (float4*)&wS[0][0];
#pragma unroll
        for (int c = 0; c < 6; ++c) dst[t + 256 * c] = src[t + 256 * c];
        if (t < 192) bS[t] = bias[t];
    }
    __syncthreads();
    int tc = t & 15, tr = t >> 4;
    int r0 = tc * 4, j0 = tr * 12;
    float acc[12][4];
#pragma unroll
    for (int j = 0; j < 12; ++j) {
        float bb = bS[j0 + j];
        acc[j][0] = bb; acc[j][1] = bb; acc[j][2] = bb; acc[j][3] = bb;
    }
#pragma unroll 2
    for (int i = 0; i < 32; ++i) {
        float4 a = *(const float4*)&hT[i][r0];
#pragma unroll
        for (int jj = 0; jj < 3; ++jj) {
            float4 w = *(const float4*)&wS[i][j0 + jj * 4];
            int jb = jj * 4;
            acc[jb+0][0] += w.x*a.x; acc[jb+0][1] += w.x*a.y; acc[jb+0][2] += w.x*a.z; acc[jb+0][3] += w.x*a.w;
            acc[jb+1][0] += w.y*a.x; acc[jb+1][1] += w.y*a.y; acc[jb+1][2] += w.y*a.z; acc[jb+1][3] += w.y*a.w;
            acc[jb+2][0] += w.z*a.x; acc[jb+2][1] += w.z*a.y; acc[jb+2][2] += w.z*a.z; acc[jb+2][3] += w.z*a.w;
            acc[jb+3][0] += w.w*a.x; acc[jb+3][1] += w.w*a.y; acc[jb+3][2] += w.w*a.z; acc[jb+3][3] += w.w*a.w;
        }
    }
    __syncthreads();
    // stage W phase 1
    {
        const float4* src = (const float4*)(wT + 32 * 192);
        float4* dst = (float4*)&wS[0][0];
#pragma unroll
        for (int c = 0; c < 6; ++c) dst[t + 256 * c] = src[t + 256 * c];
    }
    __syncthreads();
#pragma unroll 2
    for (int i = 0; i < 32; ++i) {
        float4 a = *(const float4*)&hT[32 + i][r0];
#pragma unroll
        for (int jj = 0; jj < 3; ++jj) {
            float4 w = *(const float4*)&wS[i][j0 + jj * 4];
            int jb = jj * 4;
            acc[jb+0][0] += w.x*a.x; acc[jb+0][1] += w.x*a.y; acc[jb+0][2] += w.x*a.z; acc[jb+0][3] += w.x*a.w;
            acc[jb+1][0] += w.y*a.x; acc[jb+1][1] += w.y*a.y; acc[jb+1][2] += w.y*a.z; acc[jb+1][3] += w.y*a.w;
            acc[jb+2][0] += w.z*a.x; acc[jb+2][1] += w.z*a.y; acc[jb+2][2] += w.z*a.z; acc[jb+2][3] += w.z*a.w;
            acc[jb+3][0] += w.w*a.x; acc[jb+3][1] += w.w*a.y; acc[jb+3][2] += w.w*a.z; acc[jb+3][3] += w.w*a.w;
        }
    }
    // epilogue
#pragma unroll
    for (int j = 0; j < 12; ++j) {
        int jj = j0 + j;
        int cc = jj & 63;
        float* dst = (jj < 64) ? q : (jj < 128) ? k : v;
#pragma unroll
        for (int r = 0; r < 4; ++r) {
            int row = row0 + r0 + r;
            int idx;
            if (spatial_layout) {
                int bs = row >> 9, n = row & 511;
                idx = ((bs * 8 + (cc >> 3)) * 512 + n) * 8 + (cc & 7);
            } else {
                idx = row * 64 + cc;
            }
            dst[idx] = acc[j][r];
        }
    }
}

// ---------------- spatial attention v2: block per (bs,hd), K/V in LDS --------
// q,k,v in [bs][hd][n][8] layout. 2 queries/thread. Mask column streamed.
__global__ __launch_bounds__(256) void spatial_attn_kernel(
    const float* __restrict__ q, const float* __restrict__ k, const float* __restrict__ v,
    const u32* __restrict__ maskT, float* __restrict__ h) {
    __shared__ float Ks[NNODE * DHEAD];
    __shared__ float Vs[NNODE * DHEAD];
    int bx = blockIdx.x;            // bs*8 + hd
    int bs = bx >> 3, hd = bx & 7;
    int base = bx * (NNODE * DHEAD);
    int t = threadIdx.x;
    {
        const float4* kg = (const float4*)(k + base);
        const float4* vg = (const float4*)(v + base);
        float4* kl = (float4*)Ks;
        float4* vl = (float4*)Vs;
#pragma unroll
        for (int c = 0; c < 4; ++c) {
            kl[t + 256 * c] = kg[t + 256 * c];
            vl[t + 256 * c] = vg[t + 256 * c];
        }
    }
    __syncthreads();
    int nA = t, nB = t + 256;
    const float* qpA = q + base + nA * 8;
    const float* qpB = q + base + nB * 8;
    float4 qa0 = *(const float4*)qpA, qa1 = *(const float4*)(qpA + 4);
    float4 qb0 = *(const float4*)qpB, qb1 = *(const float4*)(qpB + 4);
    float4 accA0 = {0,0,0,0}, accA1 = {0,0,0,0}, accB0 = {0,0,0,0}, accB1 = {0,0,0,0};
    float lA = 0.f, lB = 0.f;
    for (int w = 0; w < 16; ++w) {
        u32 wa = maskT[nA * 16 + w];
        u32 wb = maskT[nB * 16 + w];
        int mbase = w << 5;
#pragma unroll 4
        for (int mm = 0; mm < 32; ++mm) {
            int m8 = (mbase + mm) << 3;
            float4 k0 = *(const float4*)&Ks[m8];
            float4 k1 = *(const float4*)&Ks[m8 + 4];
            float4 v0 = *(const float4*)&Vs[m8];
            float4 v1 = *(const float4*)&Vs[m8 + 4];
            float sA = qa0.x*k0.x + qa0.y*k0.y + qa0.z*k0.z + qa0.w*k0.w +
                       qa1.x*k1.x + qa1.y*k1.y + qa1.z*k1.z + qa1.w*k1.w;
            float sB = qb0.x*k0.x + qb0.y*k0.y + qb0.z*k0.z + qb0.w*k0.w +
                       qb1.x*k1.x + qb1.y*k1.y + qb1.z*k1.z + qb1.w*k1.w;
            float eA = ((wa >> mm) & 1u) ? __expf(sA * SCALE) : 0.f;
            float eB = ((wb >> mm) & 1u) ? __expf(sB * SCALE) : 0.f;
            lA += eA; lB += eB;
            accA0.x += eA*v0.x; accA0.y += eA*v0.y; accA0.z += eA*v0.z; accA0.w += eA*v0.w;
            accA1.x += eA*v1.x; accA1.y += eA*v1.y; accA1.z += eA*v1.z; accA1.w += eA*v1.w;
            accB0.x += eB*v0.x; accB0.y += eB*v0.y; accB0.z += eB*v0.z; accB0.w += eB*v0.w;
            accB1.x += eB*v1.x; accB1.y += eB*v1.y; accB1.z += eB*v1.z; accB1.w += eB*v1.w;
        }
    }
    if (lA == 0.f) {   // fully-masked row: reference -> uniform mean(v)
        for (int m = 0; m < NNODE; ++m) {
            float4 v0 = *(const float4*)&Vs[m * 8];
            float4 v1 = *(const float4*)&Vs[m * 8 + 4];
            accA0.x += v0.x; accA0.y += v0.y; accA0.z += v0.z; accA0.w += v0.w;
            accA1.x += v1.x; accA1.y += v1.y; accA1.z += v1.z; accA1.w += v1.w;
        }
        lA = (float)NNODE;
    }
    if (lB == 0.f) {
        for (int m = 0; m < NNODE; ++m) {
            float4 v0 = *(const float4*)&Vs[m * 8];
            float4 v1 = *(const float4*)&Vs[m * 8 + 4];
            accB0.x += v0.x; accB0.y += v0.y; accB0.z += v0.z; accB0.w += v0.w;
            accB1.x += v1.x; accB1.y += v1.y; accB1.z += v1.z; accB1.w += v1.w;
        }
        lB = (float)NNODE;
    }
    float iA = 1.f / lA, iB = 1.f / lB;
    // output row-major h[(bs*512+n)*64 + hd*8 + d]
    float* oA = h + (bs * 512 + nA) * 64 + hd * 8;
    float* oB = h + (bs * 512 + nB) * 64 + hd * 8;
    *(float4*)oA       = make_float4(accA0.x*iA, accA0.y*iA, accA0.z*iA, accA0.w*iA);
    *(float4*)(oA + 4) = make_float4(accA1.x*iA, accA1.y*iA, accA1.z*iA, accA1.w*iA);
    *(float4*)oB       = make_float4(accB0.x*iB, accB0.y*iB, accB0.z*iB, accB0.w*iB);
    *(float4*)(oB + 4) = make_float4(accB1.x*iB, accB1.y*iB, accB1.z*iB, accB1.w*iB);
}

// ---------------- temporal attention: thread per (b,s,n,h), loop t (S=12) ----
// q,k,v row-major [row][64]
__global__ __launch_bounds__(256) void temporal_attn_kernel(
    const float* __restrict__ q, const float* __restrict__ k, const float* __restrict__ v,
    float* __restrict__ h) {
    int t    = blockIdx.x * blockDim.x + threadIdx.x;  // ((b*S+sq)*N + n)*8 + hd
    int hd   = t & 7;
    int n    = (t >> 3) & (NNODE - 1);
    int rest = t >> 12;  // b*S + sq
    int b    = rest / SS;
    const float* qp = q + (rest * NNODE + n) * HIDN + hd * DHEAD;
    float4 qa = *(const float4*)qp;
    float4 qc = *(const float4*)(qp + 4);
    const float* kbase = k + (b * SS * NNODE + n) * HIDN + hd * DHEAD;
    const float* vbase = v + (b * SS * NNODE + n) * HIDN + hd * DHEAD;
    float s[SS];
#pragma unroll
    for (int tt = 0; tt < SS; ++tt) {
        const float* kp = kbase + tt * (NNODE * HIDN);
        float4 ka = *(const float4*)kp;
        float4 kc = *(const float4*)(kp + 4);
        s[tt] = (qa.x * ka.x + qa.y * ka.y + qa.z * ka.z + qa.w * ka.w +
                 qc.x * kc.x + qc.y * kc.y + qc.z * kc.z + qc.w * kc.w) * SCALE;
    }
    float mx = s[0];
#pragma unroll
    for (int tt = 1; tt < SS; ++tt) mx = fmaxf(mx, s[tt]);
    float l = 0.f;
#pragma unroll
    for (int tt = 0; tt < SS; ++tt) { s[tt] = __expf(s[tt] - mx); l += s[tt]; }
    float a0 = 0.f, a1 = 0.f, a2 = 0.f, a3 = 0.f, a4 = 0.f, a5 = 0.f, a6 = 0.f, a7 = 0.f;
#pragma unroll
    for (int tt = 0; tt < SS; ++tt) {
        const float* vp = vbase + tt * (NNODE * HIDN);
        float4 va = *(const float4*)vp;
        float4 vc = *(const float4*)(vp + 4);
        float e = s[tt];
        a0 += e * va.x; a1 += e * va.y; a2 += e * va.z; a3 += e * va.w;
        a4 += e * vc.x; a5 += e * vc.y; a6 += e * vc.z; a7 += e * vc.w;
    }
    float inv = 1.f / l;
    float* op = h + (rest * NNODE + n) * HIDN + hd * DHEAD;
    *(float4*)op       = make_float4(a0 * inv, a1 * inv, a2 * inv, a3 * inv);
    *(float4*)(op + 4) = make_float4(a4 * inv, a5 * inv, a6 * inv, a7 * inv);
}

// ---------------- output projection: h[:, S-1] @ WoutT + bout ----------------
__global__ void out_proj_kernel(const float* __restrict__ h, const float* __restrict__ W,
                                const float* __restrict__ b, void* __restrict__ out,
                                const int* __restrict__ flagp) {
    int t = blockIdx.x * blockDim.x + threadIdx.x;  // (b*N + n)*3 + c
    if (t >= BB * NNODE * 3) return;
    int c  = t % 3;
    int bn = t / 3;
    int n  = bn & (NNODE - 1);
    int bb = bn >> 9;
    const float* hp = h + ((bb * SS + (SS - 1)) * NNODE + n) * HIDN;
    const float* wp = W + c * HIDN;
    float a = b[c];
#pragma unroll
    for (int i = 0; i < HIDN; i += 4) {
        float4 h4 = *(const float4*)(hp + i);
        float4 w4 = *(const float4*)(wp + i);
        a += h4.x * w4.x + h4.y * w4.y + h4.z * w4.z + h4.w * w4.w;
    }
    if (*flagp) ((float*)out)[t] = a;
    else        ((__hip_bfloat16*)out)[t] = __float2bfloat16(a);
}

extern "C" void kernel_launch(void* const* d_in, const int* in_sizes, int n_in,
                              void* d_out, int out_size, void* d_ws, size_t ws_size,
                              hipStream_t stream) {
    const int* ei = (const int*)d_in[1];

    float* ws = (float*)d_ws;
    int*   flag   = (int*)ws;              // 64 floats reserved
    float* Win_f  = ws + 64;
    float* bin_f  = ws + 256;
    float* Wqs_f  = ws + 320;
    float* bqs_f  = ws + 8512;
    float* Wks_f  = ws + 8640;
    float* bks_f  = ws + 16832;
    float* Wvs_f  = ws + 16960;
    float* bvs_f  = ws + 25152;
    float* Wqt_f  = ws + 25280;
    float* bqt_f  = ws + 33472;
    float* Wkt_f  = ws + 33600;
    float* bkt_f  = ws + 41792;
    float* Wvt_f  = ws + 41920;
    float* bvt_f  = ws + 50112;
    float* Wout_f = ws + 50240;
    float* bout_f = ws + 50432;
    float* xf     = ws + 50496;            // 73728
    u32*   maskT  = (u32*)(ws + 124224);   // 8192 u32
    float* wTs    = ws + 132416;           // 2*12288
    float* wTt    = ws + 157000 - 8;       // = 156992; 2*12288
    float* bsp    = ws + 181568;           // 2*192
    float* btp    = ws + 181952;           // 2*192
    float* hbuf   = ws + 182336;           // 1572864 each
    float* qbuf   = hbuf + ROWS * HIDN;
    float* kbuf   = qbuf + ROWS * HIDN;
    float* vbuf   = kbuf + ROWS * HIDN;
    // total ws use ~25.9 MB

    CvtArgs ca;
    const void* srcs[17] = {d_in[2], d_in[3], d_in[4], d_in[5], d_in[6], d_in[7],
                            d_in[8], d_in[9], d_in[10], d_in[11], d_in[12], d_in[13],
                            d_in[14], d_in[15], d_in[16], d_in[17], d_in[0]};
    float* dsts[17] = {Win_f, bin_f, Wqs_f, bqs_f, Wks_f, bks_f, Wvs_f, bvs_f,
                       Wqt_f, bqt_f, Wkt_f, bkt_f, Wvt_f, bvt_f, Wout_f, bout_f, xf};
    int    ns[17]   = {192, 64, 8192, 128, 8192, 128, 8192, 128,
                       8192, 128, 8192, 128, 8192, 128, 192, 3, XELEMS};
    for (int i = 0; i < 17; ++i) { ca.src[i] = srcs[i]; ca.dst[i] = dsts[i]; ca.n[i] = ns[i]; }

    hipMemsetAsync(flag, 0, sizeof(int), stream);
    hipMemsetAsync(maskT, 0, 8192 * sizeof(u32), stream);
    detect_kernel<<<64, 256, 0, stream>>>((const u16*)d_in[0], flag);
    convert_kernel<<<dim3((XELEMS + 255) / 256, 17), 256, 0, stream>>>(ca, flag);
    pack_kernel<<<dim3(48, 2), 256, 0, stream>>>(Wqs_f, bqs_f, Wks_f, bks_f, Wvs_f, bvs_f, wTs, bsp);
    pack_kernel<<<dim3(48, 2), 256, 0, stream>>>(Wqt_f, bqt_f, Wkt_f, bkt_f, Wvt_f, bvt_f, wTt, btp);
    scatter_mask_kernel<<<NEDGE / 256, 256, 0, stream>>>(ei, maskT);
    input_proj_kernel<<<ROWS * HIDN / 256, 256, 0, stream>>>(xf, Win_f, bin_f, hbuf);

    const int GEMM_BLOCKS = ROWS / 64;                       // 384
    const int ATTN_BLOCKS = BB * SS * NHEADS * NNODE / 256;  // 768 (temporal)
    for (int l = 0; l < NLAY; ++l) {
        // spatial
        qkv_gemm_kernel<<<GEMM_BLOCKS, 256, 0, stream>>>(
            hbuf, wTs + l * 12288, bsp + l * 192, qbuf, kbuf, vbuf, 1);
        spatial_attn_kernel<<<BB * SS * NHEADS, 256, 0, stream>>>(qbuf, kbuf, vbuf, maskT, hbuf);
        // temporal
        qkv_gemm_kernel<<<GEMM_BLOCKS, 256, 0, stream>>>(
            hbuf, wTt + l * 12288, btp + l * 192, qbuf, kbuf, vbuf, 0);
        temporal_attn_kernel<<<ATTN_BLOCKS, 256, 0, stream>>>(qbuf, kbuf, vbuf, hbuf);
    }
    out_proj_kernel<<<(BB * NNODE * 3 + 255) / 256, 256, 0, stream>>>(
        hbuf, Wout_f, bout_f, d_out, flag);
}